// Round 2
// baseline (1002.063 us; speedup 1.0000x reference)
//
#include <hip/hip_runtime.h>
#include <hip/hip_bf16.h>

// Problem constants
#define NROWS   32768     // 32*32*32
#define DIMD    256
#define NATOMS  1024
#define SPAR    8

// ---------------------------------------------------------------------------
// dict atom squared norms
__global__ void vq_norms(const float* __restrict__ dict_w, float* __restrict__ dnorm) {
    int k = blockIdx.x;          // 1024 blocks
    int lane = threadIdx.x;      // 64 threads
    float4 v = *(const float4*)&dict_w[(size_t)k * DIMD + lane * 4];
    float s = v.x * v.x + v.y * v.y + v.z * v.z + v.w * v.w;
#pragma unroll
    for (int o = 32; o > 0; o >>= 1) s += __shfl_down(s, o, 64);
    if (lane == 0) dnorm[k] = s;
}

// ---------------------------------------------------------------------------
// top-8 insert into sorted (ascending) register array. key = sortable(dist)<<32 | idx
__device__ __forceinline__ void top8_insert(unsigned long long ck, float cl,
                                            unsigned long long (&key)[8], float (&lg)[8]) {
    bool b[8];
#pragma unroll
    for (int j = 0; j < 8; ++j) b[j] = ck < key[j];
#pragma unroll
    for (int j = 7; j >= 1; --j) {
        unsigned long long t = b[j - 1] ? key[j - 1] : ck;
        float tl = b[j - 1] ? lg[j - 1] : cl;
        key[j] = b[j] ? t : key[j];
        lg[j]  = b[j] ? tl : lg[j];
    }
    key[0] = b[0] ? ck : key[0];
    lg[0]  = b[0] ? cl : lg[0];
}

// ---------------------------------------------------------------------------
// Main fused kernel: LDS-free dual GEMM (logits + dots) from L2-resident
// operands + online softmax-sum + online top-8 + rep_sparse row fill.
// 64 rows x 1024 atoms per block, 256 threads, 512 blocks.
__global__ __launch_bounds__(256, 3) void vq_main(
    const float* __restrict__ z_e, const float* __restrict__ dict_w,
    const float* __restrict__ rep_w, const float* __restrict__ rep_b,
    const float* __restrict__ dnorm,
    float* __restrict__ rep_sparse, int* __restrict__ idx_out,
    float* __restrict__ w_out, int* __restrict__ counts)
{
    __shared__ __align__(16) char smem[35328];
    auto Ll = reinterpret_cast<float (*)[69]>(smem);            // [64][69] logits
    auto Ld = reinterpret_cast<float (*)[69]>(smem + 17664);    // [64][69] sel values
    // end-of-kernel overlay (barrier separated):
    unsigned long long* mk = reinterpret_cast<unsigned long long*>(smem);  // [64][4][8] 16384 B
    float* ml   = reinterpret_cast<float*>(smem + 16384);                  // [64][4][8]  8192 B
    float* msum = reinterpret_cast<float*>(smem + 24576);                  // [64][4]     1024 B

    const int tid = threadIdx.x;
    const int row0 = blockIdx.x * 64;
    const int bb  = row0 >> 10;          // batch index (64 | 1024, no straddle)
    const int hw0 = row0 & 1023;
    const float* zbase = z_e + (size_t)bb * (DIMD * 1024) + hw0;

    // selection state: thread = (row selr, part selp); part scans 16 atoms per tile
    const int selr = tid & 63, selp = tid >> 6;
    unsigned long long key[8];
    float lg[8];
    float sume = 0.f;
#pragma unroll
    for (int j = 0; j < 8; ++j) { key[j] = ~0ull; lg[j] = 0.f; }

    // GEMM thread mapping: 16 row-groups x 16 atom-groups of 4x4
    const int tm = tid & 15, tk = tid >> 4;
    const int am = tm * 4, ak = tk * 4;
    const float* zp = zbase + am;        // lane's A column base

    for (int kt = 0; kt < 16; ++kt) {
        const int k0 = kt * 64;
        const float* Rp = rep_w  + (size_t)(k0 + ak) * DIMD;
        const float* Wp = dict_w + (size_t)(k0 + ak) * DIMD;
        float accR[4][4] = {{0}}, accW[4][4] = {{0}};

#pragma unroll 2
        for (int d = 0; d < DIMD; d += 4) {
            float4 av[4], rv[4], wv[4];
#pragma unroll
            for (int u = 0; u < 4; ++u)
                av[u] = *(const float4*)&zp[(size_t)(d + u) * 1024];
#pragma unroll
            for (int j = 0; j < 4; ++j) {
                rv[j] = *(const float4*)&Rp[(size_t)j * DIMD + d];
                wv[j] = *(const float4*)&Wp[(size_t)j * DIMD + d];
            }
#pragma unroll
            for (int u = 0; u < 4; ++u) {
#pragma unroll
                for (int i = 0; i < 4; ++i) {
                    float a = ((const float*)&av[u])[i];
#pragma unroll
                    for (int j = 0; j < 4; ++j) {
                        accR[i][j] = fmaf(a, ((const float*)&rv[j])[u], accR[i][j]);
                        accW[i][j] = fmaf(a, ((const float*)&wv[j])[u], accW[i][j]);
                    }
                }
            }
        }

        // publish tile results (logit with bias; selection value = ||dict||^2 - 2*dot)
        __syncthreads();   // previous tile's scan done before overwrite
#pragma unroll
        for (int i = 0; i < 4; ++i)
#pragma unroll
            for (int j = 0; j < 4; ++j) {
                int gk = k0 + ak + j;
                Ll[am + i][ak + j] = accR[i][j] + rep_b[gk];
                Ld[am + i][ak + j] = dnorm[gk] - 2.0f * accW[i][j];
            }
        __syncthreads();

        // online scan: each of 4 parts per row handles 16 atoms
        for (int t = 0; t < 16; ++t) {
            int kl = selp * 16 + t;
            float l = Ll[selr][kl];
            float v = Ld[selr][kl];
            sume += expf(l);
            unsigned int u = __float_as_uint(v);
            u = u ^ ((unsigned)((int)u >> 31) | 0x80000000u);   // monotone sortable
            unsigned long long ck = ((unsigned long long)u << 32) | (unsigned)(k0 + kl);
            if (ck < key[7]) top8_insert(ck, l, key, lg);
        }
    }

    // merge the 4 partial top-8s per row, finish softmax, scatter outputs
    __syncthreads();
    {
        int o = (selr * 4 + selp) * 8;
#pragma unroll
        for (int j = 0; j < 8; ++j) { mk[o + j] = key[j]; ml[o + j] = lg[j]; }
        msum[selr * 4 + selp] = sume;
    }
    __syncthreads();

    // all threads: zero-fill this block's 64 rows of rep_sparse (replaces memset)
    {
        float4 z4; z4.x = z4.y = z4.z = z4.w = 0.f;
        float4* rp4 = (float4*)rep_sparse + (size_t)row0 * (NATOMS / 4) + tid;
        for (int r = 0; r < 64; ++r)
            rp4[(size_t)r * (NATOMS / 4)] = z4;
    }
    __syncthreads();   // zero-fill stores drained (vmcnt(0) before barrier)

    if (tid < 64) {
        int r = tid;
        unsigned long long K[8];
        float L[8];
#pragma unroll
        for (int j = 0; j < 8; ++j) { K[j] = mk[(r * 4 + 0) * 8 + j]; L[j] = ml[(r * 4 + 0) * 8 + j]; }
        for (int p = 1; p < 4; ++p)
            for (int t = 0; t < 8; ++t) {
                unsigned long long ck = mk[(r * 4 + p) * 8 + t];
                float cl = ml[(r * 4 + p) * 8 + t];
                if (ck < K[7]) top8_insert(ck, cl, K, L);
            }
        float s = msum[r * 4] + msum[r * 4 + 1] + msum[r * 4 + 2] + msum[r * 4 + 3];
        float inv = 0.125f / s;   // rep / SPARSITY
        int row = row0 + r;
#pragma unroll
        for (int j = 0; j < 8; ++j) {
            int gidx = (int)(K[j] & 0xffffffffull);
            float wv = expf(L[j]) * inv;
            idx_out[row * 8 + j] = gidx;
            w_out[row * 8 + j] = wv;
            rep_sparse[(size_t)row * NATOMS + gidx] = wv;
            atomicAdd(&counts[gidx], 1);
        }
    }
}

// ---------------------------------------------------------------------------
// Reconstruct z_dl, write z_st (NCHW), accumulate squared-error partials.
// 32 rows per block, 1024 blocks, 256 threads.
__global__ __launch_bounds__(256, 2) void vq_recon(
    const float* __restrict__ z_e, const float* __restrict__ dict_w,
    const int* __restrict__ idx_in, const float* __restrict__ w_in,
    float* __restrict__ z_st, float* __restrict__ partials)
{
    __shared__ float zdl[32][257];
    __shared__ float red[256];
    const int tid = threadIdx.x;
    const int row0 = blockIdx.x * 32;

    // phase A: z_dl rows into LDS; lanes over d (coalesced dict reads)
    for (int r = 0; r < 32; ++r) {
        int row = row0 + r;
        float acc = 0.f;
#pragma unroll
        for (int j = 0; j < 8; ++j) {
            int ix = idx_in[row * 8 + j];
            float wv = w_in[row * 8 + j];
            acc = fmaf(wv, dict_w[(size_t)ix * DIMD + tid], acc);
        }
        zdl[r][tid] = acc;
    }
    __syncthreads();

    // phase B: coalesced NCHW read/write; lanes over rows
    const int bb = row0 >> 10, hw0 = row0 & 1023;
    const float* zb = z_e + (size_t)bb * (DIMD * 1024) + hw0;
    float* ob = z_st + (size_t)bb * (DIMD * 1024) + hw0;
    const int m = tid & 31, dg = tid >> 5;     // 8 d-groups
    float sacc = 0.f;
    for (int it = 0; it < 32; ++it) {
        int d = it * 8 + dg;
        float ze = zb[(size_t)d * 1024 + m];
        float zd = zdl[m][d];
        float diff = zd - ze;
        ob[(size_t)d * 1024 + m] = ze + diff;   // straight-through value, ref rounding path
        sacc = fmaf(diff, diff, sacc);
    }
    red[tid] = sacc;
    __syncthreads();
    for (int s = 128; s > 0; s >>= 1) {
        if (tid < s) red[tid] += red[tid + s];
        __syncthreads();
    }
    if (tid == 0) partials[blockIdx.x] = red[0];
}

// ---------------------------------------------------------------------------
// Finalize: loss and perplexity (deterministic fixed-order reductions)
__global__ void vq_final(const float* __restrict__ partials,
                         const int* __restrict__ counts,
                         float* __restrict__ out_loss, float* __restrict__ out_perp)
{
    __shared__ double dred[256];
    __shared__ float fred[256];
    const int tid = threadIdx.x;
    double s = 0.0;
    for (int i = tid; i < 1024; i += 256) s += (double)partials[i];
    dred[tid] = s;
    __syncthreads();
    for (int st = 128; st > 0; st >>= 1) {
        if (tid < st) dred[tid] += dred[tid + st];
        __syncthreads();
    }
    float ps = 0.f;
    for (int i = tid; i < NATOMS; i += 256) {
        float p = (float)counts[i] * (1.0f / 262144.0f);   // counts/(8N), exact
        ps += p * logf(p + 1e-10f);
    }
    fred[tid] = ps;
    __syncthreads();
    for (int st = 128; st > 0; st >>= 1) {
        if (tid < st) fred[tid] += fred[tid + st];
        __syncthreads();
    }
    if (tid == 0) {
        *out_loss = 0.25f * (float)(dred[0] / 8388608.0);
        *out_perp = expf(-fred[0]);
    }
}

// ---------------------------------------------------------------------------
extern "C" void kernel_launch(void* const* d_in, const int* in_sizes, int n_in,
                              void* d_out, int out_size, void* d_ws, size_t ws_size,
                              hipStream_t stream) {
    const float* z_e    = (const float*)d_in[0];
    const float* dict_w = (const float*)d_in[1];
    const float* rep_w  = (const float*)d_in[2];
    const float* rep_b  = (const float*)d_in[3];

    float* out = (float*)d_out;
    float* out_loss   = out;                      // [0]
    float* z_st       = out + 1;                  // [1 .. 8388608]
    float* out_perp   = out + 1 + 8388608;        // [8388609]
    float* rep_sparse = out + 2 + 8388608;        // [8388610 ..]

    char* ws = (char*)d_ws;
    int*   idx_out  = (int*)ws;                             // 1 MB
    float* w_out    = (float*)(ws + (1 << 20));             // 1 MB
    int*   counts   = (int*)(ws + (2 << 20));               // 4 KB
    float* dnorm    = (float*)(ws + (2 << 20) + 4096);      // 4 KB
    float* partials = (float*)(ws + (2 << 20) + 8192);      // 4 KB

    hipMemsetAsync(counts, 0, NATOMS * sizeof(int), stream);

    vq_norms<<<NATOMS, 64, 0, stream>>>(dict_w, dnorm);
    vq_main<<<NROWS / 64, 256, 0, stream>>>(z_e, dict_w, rep_w, rep_b, dnorm,
                                            rep_sparse, idx_out, w_out, counts);
    vq_recon<<<NROWS / 32, 256, 0, stream>>>(z_e, dict_w, idx_out, w_out, z_st, partials);
    vq_final<<<1, 256, 0, stream>>>(partials, counts, out_loss, out_perp);
}

// Round 3
// 349.356 us; speedup vs baseline: 2.8683x; 2.8683x over previous
//
#include <hip/hip_runtime.h>
#include <hip/hip_bf16.h>

#define NROWS   32768     // 32*32*32
#define DIMD    256
#define NATOMS  1024

typedef short  bf16x8 __attribute__((ext_vector_type(8)));
typedef float  f32x4  __attribute__((ext_vector_type(4)));

__device__ __forceinline__ unsigned short bf16rne(float f) {
    unsigned u = __float_as_uint(f);
    u = u + 0x7FFFu + ((u >> 16) & 1u);
    return (unsigned short)(u >> 16);
}
__device__ __forceinline__ float bf16tof(unsigned short h) {
    return __uint_as_float(((unsigned)h) << 16);
}

// ---------------------------------------------------------------------------
// B prep: build interleaved concat [2048][256] bf16 x 3 splits; row = atom*2 + half
// (half 0 = rep_w -> logits, half 1 = dict_w -> dists). Also dict norms.
__global__ __launch_bounds__(256) void vq_bprep(
    const float* __restrict__ rep_w, const float* __restrict__ dict_w,
    unsigned short* __restrict__ Bs, float* __restrict__ dnorm)
{
    const int tid = threadIdx.x;
    const int r = tid >> 3, c8 = tid & 7;          // 32 rows x 8 chunks
    const int out_row = blockIdx.x * 32 + r;       // 64 blocks
    const int atom = out_row >> 1, half = out_row & 1;
    const float* src = (half ? dict_w : rep_w) + (size_t)atom * DIMD + c8 * 32;
    unsigned short* p1 = Bs + (size_t)out_row * DIMD + c8 * 32;
    unsigned short* p2 = p1 + 524288;              // plane stride = 2048*256
    unsigned short* p3 = p2 + 524288;
    float ss = 0.f;
#pragma unroll
    for (int q = 0; q < 8; ++q) {
        float4 v = *(const float4*)&src[q * 4];
        float fv[4] = {v.x, v.y, v.z, v.w};
        unsigned short a1[4], a2[4], a3[4];
#pragma unroll
        for (int e = 0; e < 4; ++e) {
            float f = fv[e];
            ss = fmaf(f, f, ss);
            unsigned short b1 = bf16rne(f);  float r1 = f  - bf16tof(b1);
            unsigned short b2 = bf16rne(r1); float r2 = r1 - bf16tof(b2);
            unsigned short b3 = bf16rne(r2);
            a1[e] = b1; a2[e] = b2; a3[e] = b3;
        }
        *(ushort4*)&p1[q * 4] = make_ushort4(a1[0], a1[1], a1[2], a1[3]);
        *(ushort4*)&p2[q * 4] = make_ushort4(a2[0], a2[1], a2[2], a2[3]);
        *(ushort4*)&p3[q * 4] = make_ushort4(a3[0], a3[1], a3[2], a3[3]);
    }
    // row-sum of squares across the 8 chunk-threads (consecutive lanes)
    ss += __shfl_down(ss, 4, 8);
    ss += __shfl_down(ss, 2, 8);
    ss += __shfl_down(ss, 1, 8);
    if (half && c8 == 0) dnorm[atom] = ss;
}

// ---------------------------------------------------------------------------
// top-8 insert into sorted (ascending) register array. key = sortable(dist)<<32 | idx
__device__ __forceinline__ void top8_insert(unsigned long long ck, float cl,
                                            unsigned long long (&key)[8], float (&lg)[8]) {
    bool b[8];
#pragma unroll
    for (int j = 0; j < 8; ++j) b[j] = ck < key[j];
#pragma unroll
    for (int j = 7; j >= 1; --j) {
        unsigned long long t = b[j - 1] ? key[j - 1] : ck;
        float tl = b[j - 1] ? lg[j - 1] : cl;
        key[j] = b[j] ? t : key[j];
        lg[j]  = b[j] ? tl : lg[j];
    }
    key[0] = b[0] ? ck : key[0];
    lg[0]  = b[0] ? cl : lg[0];
}

// ---------------------------------------------------------------------------
// Main: bf16x3-split dual GEMM on MFMA + online softmax-sum + online top-8.
// 64 rows x 1024 atoms per block, 256 threads (4 waves), 512 blocks.
// Wave w owns rows [w*16, w*16+16); A held in registers (3 splits x 8 ksteps).
// Per iteration: 16 atoms -> 32 interleaved B rows staged in LDS (swizzled).
__global__ __launch_bounds__(256, 2) void vq_main(
    const float* __restrict__ z_e, const unsigned short* __restrict__ Bs,
    const float* __restrict__ rep_b, const float* __restrict__ dnorm,
    int* __restrict__ idx_out, float* __restrict__ w_out, int* __restrict__ counts)
{
    __shared__ __align__(16) char smem[57856];
    // [0,49152): B tiles, 3 splits x 32 rows x 512 B (XOR-swizzled)
    auto Ll = reinterpret_cast<float (*)[17]>(smem + 49152);   // [64][17] raw logits
    auto Ld = reinterpret_cast<float (*)[17]>(smem + 53504);   // [64][17] raw dots
    // merge overlay (over B region, barrier-separated):
    unsigned long long* mk = reinterpret_cast<unsigned long long*>(smem);  // [64][4][8]
    float* ml   = reinterpret_cast<float*>(smem + 16384);                  // [64][4][8]
    float* msum = reinterpret_cast<float*>(smem + 24576);                  // [64][4]

    const int tid = threadIdx.x;
    const int lane = tid & 63, w = tid >> 6;
    const int c = lane & 15, g = lane >> 4;
    const int row0 = blockIdx.x * 64;
    const int bb = row0 >> 10, hw0 = row0 & 1023;

    // ---- staging helper: tile it covers B rows [it*32, it*32+32), 3 splits
    auto stage = [&](int it) {
#pragma unroll
        for (int p = 0; p < 12; ++p) {
            const int s = p >> 2, ch = p & 3;
            const int off = ch * 4096 + tid * 16;                 // within-split LDS offset
            const int srcoff = off ^ (((off >> 10) & 7) << 4);    // inverse swizzle
            const char* gp = (const char*)Bs + ((size_t)s << 20)
                           + ((size_t)it << 14) + srcoff;
            char* lp = smem + s * 16384 + ch * 4096 + (w << 10);  // wave-uniform base
            __builtin_amdgcn_global_load_lds(
                (const __attribute__((address_space(1))) unsigned int*)gp,
                (__attribute__((address_space(3))) unsigned int*)lp, 16, 0, 0);
        }
    };

    stage(0);

    // ---- load this wave's 16 A-rows (fp32) and split into bf16x3 registers
    bf16x8 a[3][8];
    {
        const float* zb = z_e + (size_t)bb * (DIMD * 1024) + (hw0 + w * 16 + c);
#pragma unroll
        for (int kk = 0; kk < 8; ++kk) {
            float f[8];
#pragma unroll
            for (int e = 0; e < 8; ++e)
                f[e] = zb[(size_t)(kk * 32 + g * 8 + e) * 1024];
#pragma unroll
            for (int e = 0; e < 8; ++e) {
                float v = f[e];
                unsigned short b1 = bf16rne(v);  float r1 = v  - bf16tof(b1);
                unsigned short b2 = bf16rne(r1); float r2 = r1 - bf16tof(b2);
                unsigned short b3 = bf16rne(r2);
                a[0][kk][e] = (short)b1;
                a[1][kk][e] = (short)b2;
                a[2][kk][e] = (short)b3;
            }
        }
    }

    // selection state
    const int selr = lane, selp = w;
    unsigned long long key[8];
    float lg[8];
    float sume = 0.f;
#pragma unroll
    for (int j = 0; j < 8; ++j) { key[j] = ~0ull; lg[j] = 0.f; }

    const int swz = (c & 7) << 4;

    for (int it = 0; it < 64; ++it) {
        __syncthreads();     // B(it) staged; Ll/Ld free (scan(it-1) done)

        f32x4 acc0 = {0.f, 0.f, 0.f, 0.f};   // logits (even B rows)
        f32x4 acc1 = {0.f, 0.f, 0.f, 0.f};   // dict dots (odd B rows)
#pragma unroll
        for (int s = 0; s < 3; ++s) {
#pragma unroll
            for (int kk = 0; kk < 8; ++kk) {
                const int lin = (c << 10) + (kk << 6) + (g << 4);  // row 2c
                bf16x8 b0 = *(const bf16x8*)(smem + s * 16384 + (lin ^ swz));
                bf16x8 b1 = *(const bf16x8*)(smem + s * 16384 + ((lin + 512) ^ swz));
                acc0 = __builtin_amdgcn_mfma_f32_16x16x32_bf16(a[s][kk], b0, acc0, 0, 0, 0);
                acc1 = __builtin_amdgcn_mfma_f32_16x16x32_bf16(a[s][kk], b1, acc1, 0, 0, 0);
            }
        }

        // publish: C frag layout col=lane&15, row=(lane>>4)*4+reg
#pragma unroll
        for (int r = 0; r < 4; ++r) {
            const int rr = (w << 4) + (g << 2) + r;
            Ll[rr][c] = acc0[r];
            Ld[rr][c] = acc1[r];
        }
        __syncthreads();     // publishes visible; B(it) reads done

        if (it < 63) stage(it + 1);   // overlaps with scan below

        // online scan: 4 parts x 4 atoms per row
        const int c0 = it << 4;
#pragma unroll
        for (int j = 0; j < 4; ++j) {
            const int aIdx = (selp << 2) + j;
            const int ga = c0 + aIdx;
            float l = Ll[selr][aIdx] + rep_b[ga];
            float v = dnorm[ga] - 2.0f * Ld[selr][aIdx];
            sume += expf(l);
            unsigned u = __float_as_uint(v);
            u ^= ((unsigned)((int)u >> 31) | 0x80000000u);
            unsigned long long ck = ((unsigned long long)u << 32) | (unsigned)ga;
            if (ck < key[7]) top8_insert(ck, l, key, lg);
        }
    }

    // merge the 4 partial top-8s per row, finish softmax, emit idx/w/counts
    __syncthreads();
    {
        const int o = (selr * 4 + selp) * 8;
#pragma unroll
        for (int j = 0; j < 8; ++j) { mk[o + j] = key[j]; ml[o + j] = lg[j]; }
        msum[selr * 4 + selp] = sume;
    }
    __syncthreads();
    if (tid < 64) {
        const int r = tid;
        unsigned long long K[8];
        float L[8];
#pragma unroll
        for (int j = 0; j < 8; ++j) { K[j] = mk[(r * 4) * 8 + j]; L[j] = ml[(r * 4) * 8 + j]; }
        for (int p = 1; p < 4; ++p)
            for (int t = 0; t < 8; ++t) {
                unsigned long long ck = mk[(r * 4 + p) * 8 + t];
                float cl = ml[(r * 4 + p) * 8 + t];
                if (ck < K[7]) top8_insert(ck, cl, K, L);
            }
        const float s = msum[r * 4] + msum[r * 4 + 1] + msum[r * 4 + 2] + msum[r * 4 + 3];
        const float inv = 0.125f / s;   // softmax / SPARSITY
        const int row = row0 + r;
#pragma unroll
        for (int j = 0; j < 8; ++j) {
            const int gidx = (int)(K[j] & 0xffffffffull);
            const float wv = expf(L[j]) * inv;
            idx_out[row * 8 + j] = gidx;
            w_out[row * 8 + j] = wv;
            atomicAdd(&counts[gidx], 1);
        }
    }
}

// ---------------------------------------------------------------------------
// rep_sparse: zero-fill + scatter (runs after vq_main; also wipes Bs scratch)
__global__ __launch_bounds__(256) void vq_fill(
    const int* __restrict__ idx_in, const float* __restrict__ w_in,
    float* __restrict__ rep_sparse)
{
    const int tid = threadIdx.x;
    const int row0 = blockIdx.x * 64;
    float4 z4 = {0.f, 0.f, 0.f, 0.f};
    float4* rp4 = (float4*)rep_sparse + (size_t)row0 * (NATOMS / 4) + tid;
    for (int r = 0; r < 64; ++r)
        rp4[(size_t)r * (NATOMS / 4)] = z4;
    __syncthreads();
    if (tid < 64) {
        const int row = row0 + tid;
#pragma unroll
        for (int j = 0; j < 8; ++j)
            rep_sparse[(size_t)row * NATOMS + idx_in[row * 8 + j]] = w_in[row * 8 + j];
    }
}

// ---------------------------------------------------------------------------
// Reconstruct z_dl, write z_st (NCHW), accumulate squared-error partials.
__global__ __launch_bounds__(256, 2) void vq_recon(
    const float* __restrict__ z_e, const float* __restrict__ dict_w,
    const int* __restrict__ idx_in, const float* __restrict__ w_in,
    float* __restrict__ z_st, float* __restrict__ partials)
{
    __shared__ float zdl[32][257];
    __shared__ float red[256];
    const int tid = threadIdx.x;
    const int row0 = blockIdx.x * 32;

    for (int r = 0; r < 32; ++r) {
        const int row = row0 + r;
        float acc = 0.f;
#pragma unroll
        for (int j = 0; j < 8; ++j) {
            const int ix = idx_in[row * 8 + j];
            const float wv = w_in[row * 8 + j];
            acc = fmaf(wv, dict_w[(size_t)ix * DIMD + tid], acc);
        }
        zdl[r][tid] = acc;
    }
    __syncthreads();

    const int bb = row0 >> 10, hw0 = row0 & 1023;
    const float* zb = z_e + (size_t)bb * (DIMD * 1024) + hw0;
    float* ob = z_st + (size_t)bb * (DIMD * 1024) + hw0;
    const int m = tid & 31, dg = tid >> 5;
    float sacc = 0.f;
    for (int itr = 0; itr < 32; ++itr) {
        const int d = itr * 8 + dg;
        const float ze = zb[(size_t)d * 1024 + m];
        const float zd = zdl[m][d];
        const float diff = zd - ze;
        ob[(size_t)d * 1024 + m] = ze + diff;
        sacc = fmaf(diff, diff, sacc);
    }
    red[tid] = sacc;
    __syncthreads();
    for (int s = 128; s > 0; s >>= 1) {
        if (tid < s) red[tid] += red[tid + s];
        __syncthreads();
    }
    if (tid == 0) partials[blockIdx.x] = red[0];
}

// ---------------------------------------------------------------------------
// Finalize: loss and perplexity
__global__ void vq_final(const float* __restrict__ partials,
                         const int* __restrict__ counts,
                         float* __restrict__ out_loss, float* __restrict__ out_perp)
{
    __shared__ double dred[256];
    __shared__ float fred[256];
    const int tid = threadIdx.x;
    double s = 0.0;
    for (int i = tid; i < 1024; i += 256) s += (double)partials[i];
    dred[tid] = s;
    __syncthreads();
    for (int st = 128; st > 0; st >>= 1) {
        if (tid < st) dred[tid] += dred[tid + st];
        __syncthreads();
    }
    float ps = 0.f;
    for (int i = tid; i < NATOMS; i += 256) {
        const float p = (float)counts[i] * (1.0f / 262144.0f);
        ps += p * logf(p + 1e-10f);
    }
    fred[tid] = ps;
    __syncthreads();
    for (int st = 128; st > 0; st >>= 1) {
        if (tid < st) fred[tid] += fred[tid + st];
        __syncthreads();
    }
    if (tid == 0) {
        *out_loss = 0.25f * (float)(dred[0] / 8388608.0);
        *out_perp = expf(-fred[0]);
    }
}

// ---------------------------------------------------------------------------
extern "C" void kernel_launch(void* const* d_in, const int* in_sizes, int n_in,
                              void* d_out, int out_size, void* d_ws, size_t ws_size,
                              hipStream_t stream) {
    const float* z_e    = (const float*)d_in[0];
    const float* dict_w = (const float*)d_in[1];
    const float* rep_w  = (const float*)d_in[2];
    const float* rep_b  = (const float*)d_in[3];

    float* out = (float*)d_out;
    float* out_loss   = out;                      // [0]
    float* z_st       = out + 1;                  // [1 .. 8388608]
    float* out_perp   = out + 1 + 8388608;        // [8388609]
    float* rep_sparse = out + 2 + 8388608;        // [8388610 ..] 32768x1024

    // Bs scratch (3 MB) carved from the rep_sparse region, 16B-aligned;
    // vq_fill rewrites the whole region afterwards.
    unsigned short* Bs = (unsigned short*)(((uintptr_t)rep_sparse + 15) & ~(uintptr_t)15);

    char* ws = (char*)d_ws;
    int*   idx_out  = (int*)ws;                             // 1 MB
    float* w_out    = (float*)(ws + (1 << 20));             // 1 MB
    int*   counts   = (int*)(ws + (2 << 20));               // 4 KB
    float* dnorm    = (float*)(ws + (2 << 20) + 4096);      // 4 KB
    float* partials = (float*)(ws + (2 << 20) + 8192);      // 4 KB

    hipMemsetAsync(counts, 0, NATOMS * sizeof(int), stream);

    vq_bprep<<<64, 256, 0, stream>>>(rep_w, dict_w, Bs, dnorm);
    vq_main<<<NROWS / 64, 256, 0, stream>>>(z_e, Bs, rep_b, dnorm,
                                            idx_out, w_out, counts);
    vq_fill<<<NROWS / 64, 256, 0, stream>>>(idx_out, w_out, rep_sparse);
    vq_recon<<<NROWS / 32, 256, 0, stream>>>(z_e, dict_w, idx_out, w_out, z_st, partials);
    vq_final<<<1, 256, 0, stream>>>(partials, counts, out_loss, out_perp);
}